// Round 18
// baseline (280.772 us; speedup 1.0000x reference)
//
#include <hip/hip_runtime.h>
#include <hip/hip_bf16.h>

#define DD 768
#define HH 3072
#define NE 8
#define TOPK 2

#define BK 64
#define CAP 1536         // fixed rows/expert segment (counts ~1024 +/- 31; +16 sigma)
#define NRBMAX (CAP/128) // 12
#define NB1 (HH / 128)   // 24 col blocks, gemm1
#define NB2 (DD / 128)   // 6 col blocks, gemm2

typedef __attribute__((ext_vector_type(8))) short short8;
typedef __attribute__((ext_vector_type(4))) float f32x4;

static __device__ __forceinline__ unsigned short f2bf(float v) {
    __hip_bfloat16 b = __float2bfloat16(v);
    return *reinterpret_cast<unsigned short*>(&b);
}

// exact-GELU via A&S 7.1.26 rational erf (|err|<=1.5e-7, below bf16 quantization).
static __device__ __forceinline__ float gelu_f(float v) {
    float s = v * 0.70710678118f;
    float a = fabsf(s);
    float t = __builtin_amdgcn_rcpf(1.f + 0.3275911f * a);
    float poly = t * (0.254829592f + t * (-0.284496736f + t * (1.421413741f +
                 t * (-1.453152027f + t * 1.061405429f))));
    float erfv = 1.f - poly * __expf(-s * s);
    erfv = copysignf(erfv, s);
    return 0.5f * v * (1.f + erfv);
}

static __device__ __forceinline__ void cvt4(const float* __restrict__ src,
                                            unsigned short* __restrict__ dst, size_t j4)
{
    float4 v = *reinterpret_cast<const float4*>(&src[j4 * 4]);
    ushort4 o;
    o.x = f2bf(v.x); o.y = f2bf(v.y); o.z = f2bf(v.z); o.w = f2bf(v.w);
    *reinterpret_cast<ushort4*>(&dst[j4 * 4]) = o;
}

// ---------------- route + BOTH weight converts + bias row, one kernel ----------------
// Blocks < (T+15)/16 do the fused gate+scatter+gather; the LAST block writes the
// bias passthrough row; then ALL blocks grid-stride the w1+w2 fp32->bf16 conversion.
// tok_of[p] records the inverse map for gemm2's fused-combine epilogue.
__global__ __launch_bounds__(256) void routecvt_kernel(
    const float* __restrict__ x, const float* __restrict__ gw, const float* __restrict__ gb,
    int* __restrict__ ctrl, int* __restrict__ tok_of, float* __restrict__ wpos,
    unsigned short* __restrict__ Xe, int T, int maxP,
    const float* __restrict__ w1, const float* __restrict__ w2,
    unsigned short* __restrict__ w1b, unsigned short* __restrict__ w2b, size_t nW4,
    const float* __restrict__ bias, float* __restrict__ out)
{
    __shared__ int s_e[32], s_rank[32];
    __shared__ float s_w[32];
    __shared__ int lh[NE], lbase[NE];

    int tid = threadIdx.x;
    int w = tid >> 6, lane = tid & 63;

    if ((int)blockIdx.x * 16 < T) {
        if (tid < NE) lh[tid] = 0;
        __syncthreads();

        // ---- gate: 4 tokens per wave
#pragma unroll
        for (int j = 0; j < 4; ++j) {
            int t = blockIdx.x * 16 + w * 4 + j;
            if (t >= T) break;
            float acc[NE];
#pragma unroll
            for (int e = 0; e < NE; ++e) acc[e] = 0.f;
            const float4* xr = reinterpret_cast<const float4*>(x + (size_t)t * DD);
#pragma unroll
            for (int k = 0; k < 3; ++k) {
                float4 xv = xr[k * 64 + lane];
#pragma unroll
                for (int e = 0; e < NE; ++e) {
                    float4 gv = *reinterpret_cast<const float4*>(&gw[e * DD + (k * 64 + lane) * 4]);
                    acc[e] += xv.x * gv.x + xv.y * gv.y + xv.z * gv.z + xv.w * gv.w;
                }
            }
#pragma unroll
            for (int e = 0; e < NE; ++e) {
                float v = acc[e];
                for (int off = 32; off; off >>= 1) v += __shfl_xor(v, off, 64);
                acc[e] = v;
            }
            if (lane == 0) {
                float lg[NE];
#pragma unroll
                for (int e = 0; e < NE; ++e) lg[e] = acc[e] + gb[e];
                int i0 = 0;
#pragma unroll
                for (int e = 1; e < NE; ++e) if (lg[e] > lg[i0]) i0 = e;
                int i1 = -1;
#pragma unroll
                for (int e = 0; e < NE; ++e) {
                    if (e == i0) continue;
                    if (i1 < 0 || lg[e] > lg[i1]) i1 = e;
                }
                float m = lg[i0];
                float e0 = __expf(lg[i0] - m), e1 = __expf(lg[i1] - m);
                float s = e0 + e1;
                int slot = (w * 4 + j) * 2;
                s_e[slot]     = i0; s_w[slot]     = e0 / s; s_rank[slot]     = atomicAdd(&lh[i0], 1);
                s_e[slot + 1] = i1; s_w[slot + 1] = e1 / s; s_rank[slot + 1] = atomicAdd(&lh[i1], 1);
            }
        }
        __syncthreads();

        // ---- reserve segment ranges: 8 global atomics per block
        if (tid < NE) lbase[tid] = lh[tid] ? atomicAdd(&ctrl[8 + tid], lh[tid]) : 0;
        __syncthreads();

        // ---- scatter metadata + gather x rows -> bf16 Xe at assigned positions
#pragma unroll
        for (int j = 0; j < 4; ++j) {
            int t = blockIdx.x * 16 + w * 4 + j;
            if (t >= T) break;
            const float4* xr = reinterpret_cast<const float4*>(x + (size_t)t * DD);
            ushort4 o[3];
#pragma unroll
            for (int k = 0; k < 3; ++k) {
                float4 v = xr[k * 64 + lane];
                o[k].x = f2bf(v.x); o[k].y = f2bf(v.y); o[k].z = f2bf(v.z); o[k].w = f2bf(v.w);
            }
#pragma unroll
            for (int s = 0; s < 2; ++s) {
                int slot = (w * 4 + j) * 2 + s;
                int e = s_e[slot];
                int p = e * CAP + lbase[e] + s_rank[slot];
                p = min(p, maxP - 1);          // hard OOB guard (never hit for this input)
                if (lane == 0) { tok_of[p] = t; wpos[p] = s_w[slot]; }
#pragma unroll
                for (int k = 0; k < 3; ++k)
                    *reinterpret_cast<ushort4*>(&Xe[(size_t)p * DD + (k * 64 + lane) * 4]) = o[k];
            }
        }
    } else if (blockIdx.x == gridDim.x - 1) {
        // bias passthrough row (last block; disjoint from route range)
        if (tid < DD / 4)
            *reinterpret_cast<float4*>(&out[(size_t)T * DD + tid * 4]) =
                *reinterpret_cast<const float4*>(&bias[tid * 4]);
    }

    // ---- all blocks: grid-stride w1+w2 fp32 -> bf16
    size_t tot = 2 * nW4;
    for (size_t j = (size_t)blockIdx.x * 256 + tid; j < tot; j += (size_t)gridDim.x * 256) {
        if (j < nW4) cvt4(w1, w1b, j);
        else         cvt4(w2, w2b, j - nW4);
    }
}

// ---------------- staging: 128 rows x 64 cols bf16 tile -> LDS ----------------
// Linear LDS dest + inverse-XOR-swizzled per-lane global source (verified: 0 conflicts).
static __device__ __forceinline__ void stage_tile(
    const unsigned short* __restrict__ g, int ld, unsigned short* __restrict__ lds)
{
    int tid = threadIdx.x;
#pragma unroll
    for (int r = 0; r < 4; ++r) {
        int j = (r << 8) + tid;           // chunk idx 0..1023
        int row = j >> 3;
        int kc = (j & 7) ^ (row & 7);     // inverse swizzle on SOURCE
        __builtin_amdgcn_global_load_lds(
            (const __attribute__((address_space(1))) void*)(g + (size_t)row * ld + (kc << 3)),
            (__attribute__((address_space(3))) void*)(lds + (j << 3)),
            16, 0, 0);
    }
}

#define LDSF(base, row, kc) \
    reinterpret_cast<const short8*>(&(base)[((((row) << 3) + ((kc) ^ ((row) & 7))) << 3)])

// ---------------- BK=64 dbuf K-loop, counted vmcnt, swapped MFMA operands ----------------
static __device__ __forceinline__ void gemm_item(
    const unsigned short* __restrict__ Abase,
    const unsigned short* __restrict__ Bbase,
    int ld, int nt,
    unsigned short* __restrict__ As, unsigned short* __restrict__ Bs, // each [2][8192]
    f32x4 acc[4][4], int wr, int wc, int fr, int fq)
{
    const int BUF = 128 * 64;
    stage_tile(Abase, ld, As);
    stage_tile(Bbase, ld, Bs);
    for (int t = 0; t < nt; ++t) {
        int cur = t & 1;
        if (t + 1 < nt) {
            stage_tile(Abase + (size_t)(t + 1) * BK, ld, As + (cur ^ 1) * BUF);
            stage_tile(Bbase + (size_t)(t + 1) * BK, ld, Bs + (cur ^ 1) * BUF);
            asm volatile("s_waitcnt vmcnt(8)" ::: "memory");
        } else {
            asm volatile("s_waitcnt vmcnt(0)" ::: "memory");
        }
        __builtin_amdgcn_s_barrier();
        asm volatile("" ::: "memory");

        const unsigned short* A = As + cur * BUF;
        const unsigned short* B = Bs + cur * BUF;
        short8 a[2][4], b[2][4];
#pragma unroll
        for (int ks = 0; ks < 2; ++ks) {
            int kc = ks * 4 + fq;
#pragma unroll
            for (int m = 0; m < 4; ++m)
                a[ks][m] = *LDSF(A, wr + m * 16 + fr, kc);
#pragma unroll
            for (int n = 0; n < 4; ++n)
                b[ks][n] = *LDSF(B, wc + n * 16 + fr, kc);
        }
        __builtin_amdgcn_s_setprio(1);
#pragma unroll
        for (int ks = 0; ks < 2; ++ks)
#pragma unroll
            for (int m = 0; m < 4; ++m)
#pragma unroll
                for (int n = 0; n < 4; ++n)
                    acc[m][n] = __builtin_amdgcn_mfma_f32_16x16x32_bf16(
                        b[ks][n], a[ks][m], acc[m][n], 0, 0, 0);   // SWAPPED
        __builtin_amdgcn_s_setprio(0);
        asm volatile("s_waitcnt lgkmcnt(0)" ::: "memory");
        __builtin_amdgcn_s_barrier();
        asm volatile("" ::: "memory");
    }
}

// acc[m][n] holds D[ch][tok]: ch = colbase+wc+n*16+fq*4+r, tok = rowbase+wr+m*16+fr.

// ---------------- GEMM1: per-XCD queues (closed-form tables), H1 = gelu(...) ---------
__global__ __launch_bounds__(256, 2) void gemm1_kernel(
    const unsigned short* __restrict__ Xe, const unsigned short* __restrict__ W1b,
    const float* __restrict__ b1, unsigned short* __restrict__ H1,
    const int* __restrict__ ctrl, int* __restrict__ qcur)
{
    __shared__ unsigned short As[2 * 128 * 64];
    __shared__ unsigned short Bs[2 * 128 * 64];
    __shared__ int sh_item;
    __shared__ int nrbs[NE];
    __shared__ int tcum[192];

    int tid = threadIdx.x;
    if (tid < NE) {
        int cnt = ctrl[8 + tid];
        int nrb = (cnt + 127) >> 7;
        nrbs[tid] = nrb > NRBMAX ? NRBMAX : nrb;
    }
    __syncthreads();
    if (tid < 192) {                       // entry (q,s): q = tid/24, s = tid%24
        int q = tid / 24, s0 = tid - q * 24;
        int c = 0;
        for (int i = 0; i <= s0; ++i) c += nrbs[(q + 8 * i) / NB1];
        tcum[tid] = c;
    }
    __syncthreads();

    int lane = tid & 63, w = tid >> 6;
    int wr = (w >> 1) * 64, wc = (w & 1) * 64;
    int fr = lane & 15, fq = lane >> 4;
    int q0 = blockIdx.x & 7;   // round-robin XCD assumption (perf-only)

    for (int off = 0; off < 8; ++off) {      // own queue first, then steal
        int qq = (q0 + off) & 7;
        int qtot = tcum[qq * 24 + 23];
        for (;;) {
            if (tid == 0) sh_item = atomicAdd(&qcur[qq * 16], 1);
            __syncthreads();
            int j = sh_item;
            __syncthreads();
            if (j >= qtot) break;

            int s = 0;
            while (tcum[qq * 24 + s] <= j) ++s;
            int pair = qq + 8 * s;                    // closed-form group id
            int start = s ? tcum[qq * 24 + s - 1] : 0;
            int rb = j - start;
            int e = pair / NB1, cb = pair - e * NB1;
            int rowbase = e * CAP + (rb << 7);
            int colbase = cb << 7;

            const unsigned short* Abase = Xe + (size_t)rowbase * DD;
            const unsigned short* Bbase = W1b + (size_t)e * HH * DD + (size_t)colbase * DD;

            f32x4 acc[4][4];
#pragma unroll
            for (int m = 0; m < 4; ++m)
#pragma unroll
                for (int n = 0; n < 4; ++n) acc[m][n] = (f32x4){0.f, 0.f, 0.f, 0.f};

            gemm_item(Abase, Bbase, DD, DD / BK, As, Bs, acc, wr, wc, fr, fq);

            float4 bb[4];
#pragma unroll
            for (int n = 0; n < 4; ++n)
                bb[n] = *reinterpret_cast<const float4*>(
                    &b1[e * HH + colbase + wc + n * 16 + fq * 4]);
#pragma unroll
            for (int m = 0; m < 4; ++m) {
                int tok = rowbase + wr + m * 16 + fr;
#pragma unroll
                for (int n = 0; n < 4; ++n) {
                    int ch = colbase + wc + n * 16 + fq * 4;
                    ushort4 o;
                    o.x = f2bf(gelu_f(acc[m][n][0] + bb[n].x));
                    o.y = f2bf(gelu_f(acc[m][n][1] + bb[n].y));
                    o.z = f2bf(gelu_f(acc[m][n][2] + bb[n].z));
                    o.w = f2bf(gelu_f(acc[m][n][3] + bb[n].w));
                    *reinterpret_cast<ushort4*>(&H1[(size_t)tok * HH + ch]) = o;
                }
            }
        }
    }
}

// ---------------- GEMM2 + fused combine: out[tok] += wpos*(H1@w2^T + b2) ----------------
// Each output element receives exactly 2 contributions (top-2 experts are distinct),
// so atomicAdd into pre-zeroed out is exact (2-term fp add is order-invariant).
// Padding rows (local row >= expert count) are skipped via cnts[] guard.
__global__ __launch_bounds__(256, 2) void gemm2_kernel(
    const unsigned short* __restrict__ H1, const unsigned short* __restrict__ W2b,
    const float* __restrict__ b2, const float* __restrict__ wpos,
    const int* __restrict__ tok_of, float* __restrict__ out,
    const int* __restrict__ ctrl, int* __restrict__ qcur)
{
    __shared__ unsigned short As[2 * 128 * 64];
    __shared__ unsigned short Bs[2 * 128 * 64];
    __shared__ int sh_item;
    __shared__ int nrbs[NE], cnts[NE];
    __shared__ int tcum[48];

    int tid = threadIdx.x;
    if (tid < NE) {
        int cnt = ctrl[8 + tid];
        cnts[tid] = cnt;
        int nrb = (cnt + 127) >> 7;
        nrbs[tid] = nrb > NRBMAX ? NRBMAX : nrb;
    }
    __syncthreads();
    if (tid < 48) {                        // entry (q,s): q = tid/6, s = tid%6
        int q = tid / 6, s0 = tid - q * 6;
        int c = 0;
        for (int i = 0; i <= s0; ++i) c += nrbs[(q + 8 * i) / NB2];
        tcum[tid] = c;
    }
    __syncthreads();

    int lane = tid & 63, w = tid >> 6;
    int wr = (w >> 1) * 64, wc = (w & 1) * 64;
    int fr = lane & 15, fq = lane >> 4;
    int q0 = blockIdx.x & 7;

    for (int off = 0; off < 8; ++off) {
        int qq = (q0 + off) & 7;
        int qtot = tcum[qq * 6 + 5];
        for (;;) {
            if (tid == 0) sh_item = atomicAdd(&qcur[(8 + qq) * 16], 1);
            __syncthreads();
            int j = sh_item;
            __syncthreads();
            if (j >= qtot) break;

            int s = 0;
            while (tcum[qq * 6 + s] <= j) ++s;
            int g = qq + 8 * s;                       // closed-form group id
            int start = s ? tcum[qq * 6 + s - 1] : 0;
            int rb = j - start;
            int e = g / NB2, cb = g - e * NB2;
            int rowbase = e * CAP + (rb << 7);
            int colbase = cb << 7;

            const unsigned short* Abase = H1 + (size_t)rowbase * HH;
            const unsigned short* Bbase = W2b + (size_t)e * DD * HH + (size_t)colbase * HH;

            f32x4 acc[4][4];
#pragma unroll
            for (int m = 0; m < 4; ++m)
#pragma unroll
                for (int n = 0; n < 4; ++n) acc[m][n] = (f32x4){0.f, 0.f, 0.f, 0.f};

            gemm_item(Abase, Bbase, HH, HH / BK, As, Bs, acc, wr, wc, fr, fq);

            float4 bb[4];
#pragma unroll
            for (int n = 0; n < 4; ++n)
                bb[n] = *reinterpret_cast<const float4*>(
                    &b2[e * DD + colbase + wc + n * 16 + fq * 4]);
            int cnt_e = cnts[e];
#pragma unroll
            for (int m = 0; m < 4; ++m) {
                int p = rowbase + wr + m * 16 + fr;
                if (p - e * CAP >= cnt_e) continue;    // padding row: no contribution
                int t = tok_of[p];
                float wp = wpos[p];
                float* orow = &out[(size_t)t * DD];
#pragma unroll
                for (int n = 0; n < 4; ++n) {
                    int ch = colbase + wc + n * 16 + fq * 4;
                    atomicAdd(&orow[ch + 0], wp * (acc[m][n][0] + bb[n].x));
                    atomicAdd(&orow[ch + 1], wp * (acc[m][n][1] + bb[n].y));
                    atomicAdd(&orow[ch + 2], wp * (acc[m][n][2] + bb[n].z));
                    atomicAdd(&orow[ch + 3], wp * (acc[m][n][3] + bb[n].w));
                }
            }
        }
    }
}

extern "C" void kernel_launch(void* const* d_in, const int* in_sizes, int n_in,
                              void* d_out, int out_size, void* d_ws, size_t ws_size,
                              hipStream_t stream)
{
    const float* x    = (const float*)d_in[0];
    const float* gw   = (const float*)d_in[1];
    const float* gb   = (const float*)d_in[2];
    const float* w1   = (const float*)d_in[3];
    const float* b1   = (const float*)d_in[4];
    const float* w2   = (const float*)d_in[5];
    const float* b2   = (const float*)d_in[6];
    const float* bias = (const float*)d_in[7];
    float* out = (float*)d_out;

    int T = in_sizes[0] / DD;
    int maxP = NE * CAP + 256;   // +slack rows guard pathological overflow writes

    char* ws = (char*)d_ws;
    size_t off = 0;
    auto alloc = [&](size_t bytes) -> char* {
        char* p = ws + off;
        off += (bytes + 255) & ~(size_t)255;
        return p;
    };
    unsigned short* w1b = (unsigned short*)alloc((size_t)NE * HH * DD * 2);
    unsigned short* w2b = (unsigned short*)alloc((size_t)NE * DD * HH * 2);
    unsigned short* Xe  = (unsigned short*)alloc((size_t)maxP * DD * 2);
    unsigned short* H1  = (unsigned short*)alloc((size_t)maxP * HH * 2);
    int*    tok_of      = (int*)alloc((size_t)maxP * 4);
    float*  wpos        = (float*)alloc((size_t)maxP * 4);
    int*    ctrl        = (int*)alloc(64 * 4);     // 256 B exactly ->
    int*    qcur        = (int*)alloc(256 * 4);    // qcur directly follows

    size_t nW = (size_t)NE * HH * DD;    // elements per weight tensor
    size_t nW4 = nW / 4;                 // float4 count

    // zero ctrl+qcur (adjacent, one memset) and the output accumulator
    hipMemsetAsync(ctrl, 0, (64 + 256) * 4, stream);
    hipMemsetAsync(out, 0, ((size_t)T * DD) * 4, stream);

    hipLaunchKernelGGL(routecvt_kernel, dim3(2048), dim3(256), 0, stream,
                       x, gw, gb, ctrl, tok_of, wpos, Xe, T, maxP,
                       w1, w2, w1b, w2b, nW4, bias, out);
    hipLaunchKernelGGL(gemm1_kernel, dim3(512), dim3(256), 0, stream,
                       Xe, w1b, b1, H1, ctrl, qcur);
    hipLaunchKernelGGL(gemm2_kernel, dim3(512), dim3(256), 0, stream,
                       H1, w2b, b2, wpos, tok_of, out, ctrl, qcur);
}

// Round 19
// 209.505 us; speedup vs baseline: 1.3402x; 1.3402x over previous
//
#include <hip/hip_runtime.h>
#include <hip/hip_bf16.h>

#define DD 768
#define HH 3072
#define NE 8
#define TOPK 2

#define BK 64
#define CAP 1536         // fixed rows/expert segment (counts ~1024 +/- 31; +16 sigma)
#define NRBMAX (CAP/128) // 12
#define NB1 (HH / 128)   // 24 col blocks, gemm1
#define NB2 (DD / 128)   // 6 col blocks, gemm2

typedef __attribute__((ext_vector_type(8))) short short8;
typedef __attribute__((ext_vector_type(4))) float f32x4;

static __device__ __forceinline__ unsigned short f2bf(float v) {
    __hip_bfloat16 b = __float2bfloat16(v);
    return *reinterpret_cast<unsigned short*>(&b);
}

// exact-GELU via A&S 7.1.26 rational erf (|err|<=1.5e-7, below bf16 quantization).
static __device__ __forceinline__ float gelu_f(float v) {
    float s = v * 0.70710678118f;
    float a = fabsf(s);
    float t = __builtin_amdgcn_rcpf(1.f + 0.3275911f * a);
    float poly = t * (0.254829592f + t * (-0.284496736f + t * (1.421413741f +
                 t * (-1.453152027f + t * 1.061405429f))));
    float erfv = 1.f - poly * __expf(-s * s);
    erfv = copysignf(erfv, s);
    return 0.5f * v * (1.f + erfv);
}

static __device__ __forceinline__ void cvt4(const float* __restrict__ src,
                                            unsigned short* __restrict__ dst, size_t j4)
{
    float4 v = *reinterpret_cast<const float4*>(&src[j4 * 4]);
    ushort4 o;
    o.x = f2bf(v.x); o.y = f2bf(v.y); o.z = f2bf(v.z); o.w = f2bf(v.w);
    *reinterpret_cast<ushort4*>(&dst[j4 * 4]) = o;
}

// ---------------- route + BOTH weight converts, one kernel ----------------
// Blocks < (T+15)/16 first do the fused gate+scatter+gather; then ALL blocks
// grid-stride the w1+w2 fp32->bf16 conversion. The ~8us route phase hides under
// the BW-bound 227MB conversion. (Round-15: gemm1 has no idle tail; round-11:
// grid.sync ~50us -> banned; round-18: atomic-accumulate epilogue -> 4x write
// traffic, strictly worse than Yb scratch + combine.)
__global__ __launch_bounds__(256) void routecvt_kernel(
    const float* __restrict__ x, const float* __restrict__ gw, const float* __restrict__ gb,
    int* __restrict__ ctrl, int* __restrict__ pos_of, float* __restrict__ wpos,
    unsigned short* __restrict__ Xe, int T, int maxP,
    const float* __restrict__ w1, const float* __restrict__ w2,
    unsigned short* __restrict__ w1b, unsigned short* __restrict__ w2b, size_t nW4)
{
    __shared__ int s_e[32], s_rank[32];
    __shared__ float s_w[32];
    __shared__ int lh[NE], lbase[NE];

    int tid = threadIdx.x;
    int w = tid >> 6, lane = tid & 63;

    if ((int)blockIdx.x * 16 < T) {
        if (tid < NE) lh[tid] = 0;
        __syncthreads();

        // ---- gate: 4 tokens per wave
#pragma unroll
        for (int j = 0; j < 4; ++j) {
            int t = blockIdx.x * 16 + w * 4 + j;
            if (t >= T) break;
            float acc[NE];
#pragma unroll
            for (int e = 0; e < NE; ++e) acc[e] = 0.f;
            const float4* xr = reinterpret_cast<const float4*>(x + (size_t)t * DD);
#pragma unroll
            for (int k = 0; k < 3; ++k) {
                float4 xv = xr[k * 64 + lane];
#pragma unroll
                for (int e = 0; e < NE; ++e) {
                    float4 gv = *reinterpret_cast<const float4*>(&gw[e * DD + (k * 64 + lane) * 4]);
                    acc[e] += xv.x * gv.x + xv.y * gv.y + xv.z * gv.z + xv.w * gv.w;
                }
            }
#pragma unroll
            for (int e = 0; e < NE; ++e) {
                float v = acc[e];
                for (int off = 32; off; off >>= 1) v += __shfl_xor(v, off, 64);
                acc[e] = v;
            }
            if (lane == 0) {
                float lg[NE];
#pragma unroll
                for (int e = 0; e < NE; ++e) lg[e] = acc[e] + gb[e];
                int i0 = 0;
#pragma unroll
                for (int e = 1; e < NE; ++e) if (lg[e] > lg[i0]) i0 = e;
                int i1 = -1;
#pragma unroll
                for (int e = 0; e < NE; ++e) {
                    if (e == i0) continue;
                    if (i1 < 0 || lg[e] > lg[i1]) i1 = e;
                }
                float m = lg[i0];
                float e0 = __expf(lg[i0] - m), e1 = __expf(lg[i1] - m);
                float s = e0 + e1;
                int slot = (w * 4 + j) * 2;
                s_e[slot]     = i0; s_w[slot]     = e0 / s; s_rank[slot]     = atomicAdd(&lh[i0], 1);
                s_e[slot + 1] = i1; s_w[slot + 1] = e1 / s; s_rank[slot + 1] = atomicAdd(&lh[i1], 1);
            }
        }
        __syncthreads();

        // ---- reserve segment ranges: 8 global atomics per block
        if (tid < NE) lbase[tid] = lh[tid] ? atomicAdd(&ctrl[8 + tid], lh[tid]) : 0;
        __syncthreads();

        // ---- scatter metadata + gather x rows -> bf16 Xe at assigned positions
#pragma unroll
        for (int j = 0; j < 4; ++j) {
            int t = blockIdx.x * 16 + w * 4 + j;
            if (t >= T) break;
            const float4* xr = reinterpret_cast<const float4*>(x + (size_t)t * DD);
            ushort4 o[3];
#pragma unroll
            for (int k = 0; k < 3; ++k) {
                float4 v = xr[k * 64 + lane];
                o[k].x = f2bf(v.x); o[k].y = f2bf(v.y); o[k].z = f2bf(v.z); o[k].w = f2bf(v.w);
            }
#pragma unroll
            for (int s = 0; s < 2; ++s) {
                int slot = (w * 4 + j) * 2 + s;
                int e = s_e[slot];
                int p = e * CAP + lbase[e] + s_rank[slot];
                p = min(p, maxP - 1);          // hard OOB guard (never hit for this input)
                if (lane == 0) { pos_of[2 * t + s] = p; wpos[p] = s_w[slot]; }
#pragma unroll
                for (int k = 0; k < 3; ++k)
                    *reinterpret_cast<ushort4*>(&Xe[(size_t)p * DD + (k * 64 + lane) * 4]) = o[k];
            }
        }
    }

    // ---- all blocks: grid-stride w1+w2 fp32 -> bf16
    size_t tot = 2 * nW4;
    for (size_t j = (size_t)blockIdx.x * 256 + tid; j < tot; j += (size_t)gridDim.x * 256) {
        if (j < nW4) cvt4(w1, w1b, j);
        else         cvt4(w2, w2b, j - nW4);
    }
}

// ---------------- staging: 128 rows x 64 cols bf16 tile -> LDS ----------------
// Linear LDS dest + inverse-XOR-swizzled per-lane global source (verified: 0 conflicts).
static __device__ __forceinline__ void stage_tile(
    const unsigned short* __restrict__ g, int ld, unsigned short* __restrict__ lds)
{
    int tid = threadIdx.x;
#pragma unroll
    for (int r = 0; r < 4; ++r) {
        int j = (r << 8) + tid;           // chunk idx 0..1023
        int row = j >> 3;
        int kc = (j & 7) ^ (row & 7);     // inverse swizzle on SOURCE
        __builtin_amdgcn_global_load_lds(
            (const __attribute__((address_space(1))) void*)(g + (size_t)row * ld + (kc << 3)),
            (__attribute__((address_space(3))) void*)(lds + (j << 3)),
            16, 0, 0);
    }
}

#define LDSF(base, row, kc) \
    reinterpret_cast<const short8*>(&(base)[((((row) << 3) + ((kc) ^ ((row) & 7))) << 3)])

// ---------------- BK=64 dbuf K-loop, counted vmcnt, swapped MFMA operands ----------------
static __device__ __forceinline__ void gemm_item(
    const unsigned short* __restrict__ Abase,
    const unsigned short* __restrict__ Bbase,
    int ld, int nt,
    unsigned short* __restrict__ As, unsigned short* __restrict__ Bs, // each [2][8192]
    f32x4 acc[4][4], int wr, int wc, int fr, int fq)
{
    const int BUF = 128 * 64;
    stage_tile(Abase, ld, As);
    stage_tile(Bbase, ld, Bs);
    for (int t = 0; t < nt; ++t) {
        int cur = t & 1;
        if (t + 1 < nt) {
            stage_tile(Abase + (size_t)(t + 1) * BK, ld, As + (cur ^ 1) * BUF);
            stage_tile(Bbase + (size_t)(t + 1) * BK, ld, Bs + (cur ^ 1) * BUF);
            asm volatile("s_waitcnt vmcnt(8)" ::: "memory");
        } else {
            asm volatile("s_waitcnt vmcnt(0)" ::: "memory");
        }
        __builtin_amdgcn_s_barrier();
        asm volatile("" ::: "memory");

        const unsigned short* A = As + cur * BUF;
        const unsigned short* B = Bs + cur * BUF;
        short8 a[2][4], b[2][4];
#pragma unroll
        for (int ks = 0; ks < 2; ++ks) {
            int kc = ks * 4 + fq;
#pragma unroll
            for (int m = 0; m < 4; ++m)
                a[ks][m] = *LDSF(A, wr + m * 16 + fr, kc);
#pragma unroll
            for (int n = 0; n < 4; ++n)
                b[ks][n] = *LDSF(B, wc + n * 16 + fr, kc);
        }
        __builtin_amdgcn_s_setprio(1);
#pragma unroll
        for (int ks = 0; ks < 2; ++ks)
#pragma unroll
            for (int m = 0; m < 4; ++m)
#pragma unroll
                for (int n = 0; n < 4; ++n)
                    acc[m][n] = __builtin_amdgcn_mfma_f32_16x16x32_bf16(
                        b[ks][n], a[ks][m], acc[m][n], 0, 0, 0);   // SWAPPED
        __builtin_amdgcn_s_setprio(0);
        asm volatile("s_waitcnt lgkmcnt(0)" ::: "memory");
        __builtin_amdgcn_s_barrier();
        asm volatile("" ::: "memory");
    }
}

// acc[m][n] holds D[ch][tok]: ch = colbase+wc+n*16+fq*4+r, tok = rowbase+wr+m*16+fr.

// ---------------- GEMM1: per-XCD queues (closed-form tables), H1 = gelu(...) ---------
// Queue q's s-th panel-group is pair = q + 8s (assignment was q = pair%8 in order),
// so the cumulative-row tables are built per-block in LDS from ctrl's 8 final counts.
__global__ __launch_bounds__(256, 2) void gemm1_kernel(
    const unsigned short* __restrict__ Xe, const unsigned short* __restrict__ W1b,
    const float* __restrict__ b1, unsigned short* __restrict__ H1,
    const int* __restrict__ ctrl, int* __restrict__ qcur)
{
    __shared__ unsigned short As[2 * 128 * 64];
    __shared__ unsigned short Bs[2 * 128 * 64];
    __shared__ int sh_item;
    __shared__ int nrbs[NE];
    __shared__ int tcum[192];

    int tid = threadIdx.x;
    if (tid < NE) {
        int cnt = ctrl[8 + tid];
        int nrb = (cnt + 127) >> 7;
        nrbs[tid] = nrb > NRBMAX ? NRBMAX : nrb;
    }
    __syncthreads();
    if (tid < 192) {                       // entry (q,s): q = tid/24, s = tid%24
        int q = tid / 24, s0 = tid - q * 24;
        int c = 0;
        for (int i = 0; i <= s0; ++i) c += nrbs[(q + 8 * i) / NB1];
        tcum[tid] = c;
    }
    __syncthreads();

    int lane = tid & 63, w = tid >> 6;
    int wr = (w >> 1) * 64, wc = (w & 1) * 64;
    int fr = lane & 15, fq = lane >> 4;
    int q0 = blockIdx.x & 7;   // round-robin XCD assumption (perf-only)

    for (int off = 0; off < 8; ++off) {      // own queue first, then steal
        int qq = (q0 + off) & 7;
        int qtot = tcum[qq * 24 + 23];
        for (;;) {
            if (tid == 0) sh_item = atomicAdd(&qcur[qq * 16], 1);
            __syncthreads();
            int j = sh_item;
            __syncthreads();
            if (j >= qtot) break;

            int s = 0;
            while (tcum[qq * 24 + s] <= j) ++s;
            int pair = qq + 8 * s;                    // closed-form group id
            int start = s ? tcum[qq * 24 + s - 1] : 0;
            int rb = j - start;
            int e = pair / NB1, cb = pair - e * NB1;
            int rowbase = e * CAP + (rb << 7);
            int colbase = cb << 7;

            const unsigned short* Abase = Xe + (size_t)rowbase * DD;
            const unsigned short* Bbase = W1b + (size_t)e * HH * DD + (size_t)colbase * DD;

            f32x4 acc[4][4];
#pragma unroll
            for (int m = 0; m < 4; ++m)
#pragma unroll
                for (int n = 0; n < 4; ++n) acc[m][n] = (f32x4){0.f, 0.f, 0.f, 0.f};

            gemm_item(Abase, Bbase, DD, DD / BK, As, Bs, acc, wr, wc, fr, fq);

            float4 bb[4];
#pragma unroll
            for (int n = 0; n < 4; ++n)
                bb[n] = *reinterpret_cast<const float4*>(
                    &b1[e * HH + colbase + wc + n * 16 + fq * 4]);
#pragma unroll
            for (int m = 0; m < 4; ++m) {
                int tok = rowbase + wr + m * 16 + fr;
#pragma unroll
                for (int n = 0; n < 4; ++n) {
                    int ch = colbase + wc + n * 16 + fq * 4;
                    ushort4 o;
                    o.x = f2bf(gelu_f(acc[m][n][0] + bb[n].x));
                    o.y = f2bf(gelu_f(acc[m][n][1] + bb[n].y));
                    o.z = f2bf(gelu_f(acc[m][n][2] + bb[n].z));
                    o.w = f2bf(gelu_f(acc[m][n][3] + bb[n].w));
                    *reinterpret_cast<ushort4*>(&H1[(size_t)tok * HH + ch]) = o;
                }
            }
        }
    }
}

// ---------------- GEMM2: per-XCD queues (closed-form tables), Yb = wpos*(...) -------
__global__ __launch_bounds__(256, 2) void gemm2_kernel(
    const unsigned short* __restrict__ H1, const unsigned short* __restrict__ W2b,
    const float* __restrict__ b2, const float* __restrict__ wpos,
    float* __restrict__ Yb, const int* __restrict__ ctrl, int* __restrict__ qcur)
{
    __shared__ unsigned short As[2 * 128 * 64];
    __shared__ unsigned short Bs[2 * 128 * 64];
    __shared__ int sh_item;
    __shared__ int nrbs[NE];
    __shared__ int tcum[48];

    int tid = threadIdx.x;
    if (tid < NE) {
        int cnt = ctrl[8 + tid];
        int nrb = (cnt + 127) >> 7;
        nrbs[tid] = nrb > NRBMAX ? NRBMAX : nrb;
    }
    __syncthreads();
    if (tid < 48) {                        // entry (q,s): q = tid/6, s = tid%6
        int q = tid / 6, s0 = tid - q * 6;
        int c = 0;
        for (int i = 0; i <= s0; ++i) c += nrbs[(q + 8 * i) / NB2];
        tcum[tid] = c;
    }
    __syncthreads();

    int lane = tid & 63, w = tid >> 6;
    int wr = (w >> 1) * 64, wc = (w & 1) * 64;
    int fr = lane & 15, fq = lane >> 4;
    int q0 = blockIdx.x & 7;

    for (int off = 0; off < 8; ++off) {
        int qq = (q0 + off) & 7;
        int qtot = tcum[qq * 6 + 5];
        for (;;) {
            if (tid == 0) sh_item = atomicAdd(&qcur[(8 + qq) * 16], 1);
            __syncthreads();
            int j = sh_item;
            __syncthreads();
            if (j >= qtot) break;

            int s = 0;
            while (tcum[qq * 6 + s] <= j) ++s;
            int g = qq + 8 * s;                       // closed-form group id
            int start = s ? tcum[qq * 6 + s - 1] : 0;
            int rb = j - start;
            int e = g / NB2, cb = g - e * NB2;
            int rowbase = e * CAP + (rb << 7);
            int colbase = cb << 7;

            const unsigned short* Abase = H1 + (size_t)rowbase * HH;
            const unsigned short* Bbase = W2b + (size_t)e * DD * HH + (size_t)colbase * HH;

            f32x4 acc[4][4];
#pragma unroll
            for (int m = 0; m < 4; ++m)
#pragma unroll
                for (int n = 0; n < 4; ++n) acc[m][n] = (f32x4){0.f, 0.f, 0.f, 0.f};

            gemm_item(Abase, Bbase, HH, HH / BK, As, Bs, acc, wr, wc, fr, fq);

            float4 bb[4];
#pragma unroll
            for (int n = 0; n < 4; ++n)
                bb[n] = *reinterpret_cast<const float4*>(
                    &b2[e * DD + colbase + wc + n * 16 + fq * 4]);
#pragma unroll
            for (int m = 0; m < 4; ++m) {
                int tok = rowbase + wr + m * 16 + fr;
                float wp = wpos[tok];
#pragma unroll
                for (int n = 0; n < 4; ++n) {
                    int ch = colbase + wc + n * 16 + fq * 4;
                    float4 o;
                    o.x = wp * (acc[m][n][0] + bb[n].x);
                    o.y = wp * (acc[m][n][1] + bb[n].y);
                    o.z = wp * (acc[m][n][2] + bb[n].z);
                    o.w = wp * (acc[m][n][3] + bb[n].w);
                    *reinterpret_cast<float4*>(&Yb[(size_t)tok * DD + ch]) = o;
                }
            }
        }
    }
}

// ---------------- combine: out[t] = Yb[pos0] + Yb[pos1]; bias passthrough ----------------
__global__ __launch_bounds__(256) void combine_kernel(
    const float* __restrict__ Yb, const int* __restrict__ pos_of,
    const float* __restrict__ bias, float* __restrict__ out, int T)
{
    int i = blockIdx.x * blockDim.x + threadIdx.x;
    int total = T * (DD / 4);
    if (i < total) {
        int t = i / (DD / 4);
        int c = (i % (DD / 4)) * 4;
        int p0 = pos_of[2 * t], p1 = pos_of[2 * t + 1];
        float4 v0 = *reinterpret_cast<const float4*>(&Yb[(size_t)p0 * DD + c]);
        float4 v1 = *reinterpret_cast<const float4*>(&Yb[(size_t)p1 * DD + c]);
        float4 o;
        o.x = v0.x + v1.x; o.y = v0.y + v1.y;
        o.z = v0.z + v1.z; o.w = v0.w + v1.w;
        *reinterpret_cast<float4*>(&out[(size_t)t * DD + c]) = o;
    } else if (i < total + DD / 4) {
        int c = (i - total) * 4;
        *reinterpret_cast<float4*>(&out[(size_t)T * DD + c]) =
            *reinterpret_cast<const float4*>(&bias[c]);
    }
}

extern "C" void kernel_launch(void* const* d_in, const int* in_sizes, int n_in,
                              void* d_out, int out_size, void* d_ws, size_t ws_size,
                              hipStream_t stream)
{
    const float* x    = (const float*)d_in[0];
    const float* gw   = (const float*)d_in[1];
    const float* gb   = (const float*)d_in[2];
    const float* w1   = (const float*)d_in[3];
    const float* b1   = (const float*)d_in[4];
    const float* w2   = (const float*)d_in[5];
    const float* b2   = (const float*)d_in[6];
    const float* bias = (const float*)d_in[7];
    float* out = (float*)d_out;

    int T = in_sizes[0] / DD;
    int nA = T * TOPK;
    int maxP = NE * CAP + 256;   // +slack rows guard pathological overflow writes

    char* ws = (char*)d_ws;
    size_t off = 0;
    auto alloc = [&](size_t bytes) -> char* {
        char* p = ws + off;
        off += (bytes + 255) & ~(size_t)255;
        return p;
    };
    unsigned short* w1b = (unsigned short*)alloc((size_t)NE * HH * DD * 2);
    unsigned short* w2b = (unsigned short*)alloc((size_t)NE * DD * HH * 2);
    unsigned short* Xe  = (unsigned short*)alloc((size_t)maxP * DD * 2);
    unsigned short* H1  = (unsigned short*)alloc((size_t)maxP * HH * 2);
    float*  Yb          = (float*)alloc((size_t)maxP * DD * 4);
    int*    pos_of      = (int*)alloc((size_t)nA * 4);
    float*  wpos        = (float*)alloc((size_t)maxP * 4);
    int*    ctrl        = (int*)alloc(64 * 4);     // 256 B exactly ->
    int*    qcur        = (int*)alloc(256 * 4);    // qcur directly follows

    size_t nW = (size_t)NE * HH * DD;    // elements per weight tensor
    size_t nW4 = nW / 4;                 // float4 count

    // one memset covers ctrl (256 B) + adjacent qcur (1024 B)
    hipMemsetAsync(ctrl, 0, (64 + 256) * 4, stream);

    hipLaunchKernelGGL(routecvt_kernel, dim3(2048), dim3(256), 0, stream,
                       x, gw, gb, ctrl, pos_of, wpos, Xe, T, maxP,
                       w1, w2, w1b, w2b, nW4);
    hipLaunchKernelGGL(gemm1_kernel, dim3(512), dim3(256), 0, stream,
                       Xe, w1b, b1, H1, ctrl, qcur);
    hipLaunchKernelGGL(gemm2_kernel, dim3(512), dim3(256), 0, stream,
                       H1, w2b, b2, wpos, Yb, ctrl, qcur);
    hipLaunchKernelGGL(combine_kernel, dim3((T * (DD / 4) + DD / 4 + 255) / 256, 1, 1), dim3(256), 0, stream,
                       Yb, pos_of, bias, out, T);
}